// Round 6
// baseline (297.659 us; speedup 1.0000x reference)
//
#include <hip/hip_runtime.h>

// ---------------------------------------------------------------------------
// AgglutinativeAttention: hs->QKV proj -> morpho-biased softmax attn -> out proj
// B=4 S=1024 H=1024 NH=16 HD=64.  bf16 MFMA throughout.
// R6: GEMMs are LDS-FREE: MFMA fragments loaded global->VGPR directly with
//     1-iter software pipelining. No barriers in the K-loop at all -> loads
//     drain via fine-grained vmcnt(N), no vmcnt(0) barrier stalls, no LDS
//     bank conflicts. Operands are L2-resident (XCD swizzle kept).
// ---------------------------------------------------------------------------

#define QSCALE 0.18033688011112042f   /* 0.125 * log2(e) */
#define CB0    1.0820212806667225f    /* 0.75 * log2(e) */
#define CB1    0.5193702147200268f    /* 0.36 * log2(e) */
#define VERB2  2.8853900817779268f    /* 2.0  * log2(e) */

typedef float  f32x4   __attribute__((ext_vector_type(4)));
typedef short  s16x8   __attribute__((ext_vector_type(8)));
typedef unsigned short u16x4 __attribute__((ext_vector_type(4)));
typedef unsigned short u16x8 __attribute__((ext_vector_type(8)));

#if __has_builtin(__builtin_amdgcn_exp2f)
#define EXP2F(x) __builtin_amdgcn_exp2f(x)
#else
#define EXP2F(x) exp2f(x)
#endif

__device__ __forceinline__ unsigned short f2bf(float f) {
  union { float f; unsigned u; } a; a.f = f;
  unsigned r = a.u + 0x7fffu + ((a.u >> 16) & 1u);   // RNE
  return (unsigned short)(r >> 16);
}

// ---------------- fused prep: cvt (2048) | weight-T x4 (1024) | bias (16) ---
__global__ __launch_bounds__(256) void k_prep(
    const float* __restrict__ hs, unsigned short* __restrict__ hsb,
    const float* __restrict__ Wq, const float* __restrict__ Wk,
    const float* __restrict__ Wv, const float* __restrict__ Wo,
    unsigned short* __restrict__ Wt, const int* __restrict__ mt,
    float* __restrict__ colbias, int* __restrict__ nearest) {
  __shared__ float t[64 * 68];
  int bx = blockIdx.x, tid = threadIdx.x;
  if (bx < 2048) {
    int i = (bx * 256 + tid) * 8;
    float4 v0 = *(const float4*)(hs + i);
    float4 v1 = *(const float4*)(hs + i + 4);
    u16x8 o;
    o[0] = f2bf(v0.x); o[1] = f2bf(v0.y); o[2] = f2bf(v0.z); o[3] = f2bf(v0.w);
    o[4] = f2bf(v1.x); o[5] = f2bf(v1.y); o[6] = f2bf(v1.z); o[7] = f2bf(v1.w);
    *(u16x8*)(hsb + i) = o;
  } else if (bx < 3072) {
    int w = (bx - 2048) >> 8, tt = (bx - 2048) & 255;
    const float* W = (w == 0) ? Wq : (w == 1) ? Wk : (w == 2) ? Wv : Wo;
    unsigned short* Wd = Wt + (size_t)w * 1048576;
    int n0 = (tt & 15) * 64, k0 = (tt >> 4) * 64;
    int r = tid >> 2, c0 = (tid & 3) * 16;
    const float* src = &W[(k0 + r) * 1024 + n0 + c0];
    float4 a0 = *(const float4*)(src + 0);
    float4 a1 = *(const float4*)(src + 4);
    float4 a2 = *(const float4*)(src + 8);
    float4 a3 = *(const float4*)(src + 12);
    *(float4*)&t[r * 68 + c0 + 0]  = a0;
    *(float4*)&t[r * 68 + c0 + 4]  = a1;
    *(float4*)&t[r * 68 + c0 + 8]  = a2;
    *(float4*)&t[r * 68 + c0 + 12] = a3;
    __syncthreads();
    u16x8 o0, o1;
#pragma unroll
    for (int j = 0; j < 8; j++) {
      o0[j] = f2bf(t[(c0 + j) * 68 + r]);
      o1[j] = f2bf(t[(c0 + 8 + j) * 68 + r]);
    }
    *(u16x8*)&Wd[(n0 + r) * 1024 + k0 + c0]     = o0;
    *(u16x8*)&Wd[(n0 + r) * 1024 + k0 + c0 + 8] = o1;
  } else {
    int i = bx - 3072;
    int b = i >> 2;
    int* sm = (int*)t;
    for (int j = tid; j < 1024; j += 256) sm[j] = mt[b * 1024 + j];
    __syncthreads();
    int q = (i & 3) * 256 + tid;
    int best = 1 << 30, bj = -1;
    for (int j = 0; j < 1024; ++j) {
      int d = (q > j) ? (q - j) : (j - q);
      int dd = (sm[j] == 2) ? d : (1 << 30);
      if (dd < best) { best = dd; bj = j; }
    }
    nearest[b * 1024 + q] = bj;
    int m = sm[q];
    colbias[b * 1024 + q] = CB0 * (m == 0) + CB1 * (m == 1);
  }
}

// ---------------- MFMA GEMM, LDS-free direct-load K-loop --------------------
// MODE 0: fused QKV (grid 24x32, 128x128 tiles); Q/K swapped operands ->
//         packed u16x4 stores into [B,NH,S,HD]; V normal -> u16x4 [B,NH,HD,S].
// MODE 1: out-proj (grid 8x64, 64x128 tiles); swapped -> float4 fp32 stores.
// NOTE: last iteration prefetches 64B past the logical matrix end; all such
// reads stay inside the 48MB workspace (values unused).
template <int MODE>
__global__ __launch_bounds__(256, 3) void k_gemm(
    const unsigned short* __restrict__ A,
    const unsigned short* __restrict__ WtBase,
    const float* __restrict__ bias0, const float* __restrict__ bias1,
    const float* __restrict__ bias2,
    unsigned short* __restrict__ outB, unsigned short* __restrict__ outV,
    float* __restrict__ outF) {
  constexpr int NI = (MODE == 0) ? 4 : 2;       // A-fragments per wave
  int tid = threadIdx.x, wid = tid >> 6, lane = tid & 63;
  int c = lane & 15, quad = lane >> 4;
  int m0, wsel, n0;
  const unsigned short* Bt;
  const float* bias;
  if (MODE == 0) {
    int lin = blockIdx.x + 24 * blockIdx.y;
    int xcd = lin & 7, idx = lin >> 3;
    m0 = (((xcd >> 1) << 3) + (idx & 7)) * 128;
    int xt = (xcd & 1) * 12 + (idx >> 3);
    wsel = xt >> 3;
    n0 = (xt & 7) * 128;
    Bt = WtBase + wsel * 1048576;
    bias = (wsel == 0) ? bias0 : ((wsel == 1) ? bias1 : bias2);
  } else {
    int lin = blockIdx.x + 8 * blockIdx.y;      // grid (8, 64) -> 512 blocks
    int xcd = lin & 7, idx = lin >> 3;          // idx 0..63
    m0 = ((xcd << 3) + (idx & 7)) * 64;         // 64 m-tiles of 64 rows
    n0 = (idx >> 3) * 128;                      // 8 n-tiles
    wsel = 0; Bt = WtBase; bias = bias0;
  }
  int wm = (wid >> 1) * (NI * 16), wn = (wid & 1) * 64;
  const unsigned short* abase = A  + (size_t)(m0 + wm + c) * 1024 + quad * 8;
  const unsigned short* bbase = Bt + (size_t)(n0 + wn + c) * 1024 + quad * 8;

  f32x4 acc[NI][4];
#pragma unroll
  for (int i = 0; i < NI; i++)
#pragma unroll
    for (int j = 0; j < 4; j++) acc[i][j] = (f32x4){0.f, 0.f, 0.f, 0.f};

  bool sw = (MODE == 1) || (wsel != 2);         // swapped-operand (wave-uniform)

  s16x8 af[NI], bf[4];
#pragma unroll
  for (int i = 0; i < NI; i++) af[i] = *(const s16x8*)(abase + i * 16 * 1024);
#pragma unroll
  for (int j = 0; j < 4; j++)  bf[j] = *(const s16x8*)(bbase + j * 16 * 1024);

  if (sw) {
#pragma unroll 2
    for (int k0 = 0; k0 < 1024; k0 += 32) {
      s16x8 an[NI], bn[4];
#pragma unroll
      for (int i = 0; i < NI; i++)
        an[i] = *(const s16x8*)(abase + k0 + 32 + i * 16 * 1024);
#pragma unroll
      for (int j = 0; j < 4; j++)
        bn[j] = *(const s16x8*)(bbase + k0 + 32 + j * 16 * 1024);
#pragma unroll
      for (int i = 0; i < NI; i++)
#pragma unroll
        for (int j = 0; j < 4; j++)
          acc[i][j] = __builtin_amdgcn_mfma_f32_16x16x32_bf16(bf[j], af[i], acc[i][j], 0, 0, 0);
#pragma unroll
      for (int i = 0; i < NI; i++) af[i] = an[i];
#pragma unroll
      for (int j = 0; j < 4; j++) bf[j] = bn[j];
    }
  } else {
#pragma unroll 2
    for (int k0 = 0; k0 < 1024; k0 += 32) {
      s16x8 an[NI], bn[4];
#pragma unroll
      for (int i = 0; i < NI; i++)
        an[i] = *(const s16x8*)(abase + k0 + 32 + i * 16 * 1024);
#pragma unroll
      for (int j = 0; j < 4; j++)
        bn[j] = *(const s16x8*)(bbase + k0 + 32 + j * 16 * 1024);
#pragma unroll
      for (int i = 0; i < NI; i++)
#pragma unroll
        for (int j = 0; j < 4; j++)
          acc[i][j] = __builtin_amdgcn_mfma_f32_16x16x32_bf16(af[i], bf[j], acc[i][j], 0, 0, 0);
#pragma unroll
      for (int i = 0; i < NI; i++) af[i] = an[i];
#pragma unroll
      for (int j = 0; j < 4; j++) bf[j] = bn[j];
    }
  }

  if (MODE == 1) {
    // swapped: row=feature (4-contig), col=token -> float4 stores
#pragma unroll
    for (int j = 0; j < 4; j++) {
      int colb = n0 + wn + j * 16 + quad * 4;
      f32x4 bvv = *(const f32x4*)&bias[colb];
#pragma unroll
      for (int i = 0; i < NI; i++) {
        int s_tok = m0 + wm + i * 16 + c;
        f32x4 v = acc[i][j] + bvv;
        *(f32x4*)&outF[(size_t)s_tok * 1024 + colb] = v;
      }
    }
  } else if (wsel == 2) {
    // V normal order: row=token (4-contig) -> u16x4 into [b,h,d,s]
#pragma unroll
    for (int j = 0; j < 4; j++) {
      int col = n0 + wn + j * 16 + c;
      float bv = bias[col];
      int h = col >> 6, d = col & 63;
#pragma unroll
      for (int i = 0; i < NI; i++) {
        int row = m0 + wm + i * 16 + quad * 4;
        int bb = row >> 10, s = row & 1023;
        u16x4 pk;
#pragma unroll
        for (int r = 0; r < 4; r++) pk[r] = f2bf(acc[i][j][r] + bv);
        *(u16x4*)&outV[(size_t)(((bb * 16 + h) * 64 + d)) * 1024 + s] = pk;
      }
    }
  } else {
    // Q/K swapped: row=feature (4-contig), col=token -> u16x4 into [b,h,s,d]
    float sc = (wsel == 0) ? QSCALE : 1.0f;
#pragma unroll
    for (int j = 0; j < 4; j++) {
      int colb = n0 + wn + j * 16 + quad * 4;
      f32x4 bvv = *(const f32x4*)&bias[colb];
      int h = colb >> 6, d0 = colb & 63;
#pragma unroll
      for (int i = 0; i < NI; i++) {
        int s_tok = m0 + wm + i * 16 + c;
        int bb = s_tok >> 10, s = s_tok & 1023;
        u16x4 pk;
#pragma unroll
        for (int r = 0; r < 4; r++) pk[r] = f2bf((acc[i][j][r] + bvv[r]) * sc);
        *(u16x4*)&outB[(size_t)wsel * 4194304 + (((bb * 16 + h) * 1024 + s) * 64) + d0] = pk;
      }
    }
  }
}

// ---------------- Flash attention, 16x16x32 MFMA, streaming softmax ---------
// grid (bh=64, qt=8): all qt blocks of one bh land on one XCD. Register
// prefetch dbuf. PV swapped operands -> AO epilogue packed u16x4, no shuffle.
__global__ __launch_bounds__(256) void k_attn(
    const unsigned short* __restrict__ Q, const unsigned short* __restrict__ K,
    const unsigned short* __restrict__ Vt, const float* __restrict__ colbias,
    const int* __restrict__ nearest, unsigned short* __restrict__ AO) {
  __shared__ unsigned short Ks[64 * 72];     // [key][d]
  __shared__ unsigned short Vs[64 * 72];     // [d][key]
  __shared__ unsigned short Ps[4][32 * 72];  // per-wave [q][key]
  __shared__ float Cb[1024];
  int tid = threadIdx.x, wid = tid >> 6, lane = tid & 63;
  int c = lane & 15, quad = lane >> 4;
  int bh = blockIdx.x, qt = blockIdx.y;
  int b = bh >> 4, head = bh & 15;
  int q0 = qt * 128, wq = wid * 32;
  const unsigned short* Qg = Q  + (size_t)(bh * 1024 + q0 + wq) * 64;
  const unsigned short* Kg = K  + (size_t)bh * 1024 * 64;
  const unsigned short* Vg = Vt + (size_t)bh * 64 * 1024;

  *(float4*)&Cb[tid * 4] = *(const float4*)&colbias[b * 1024 + tid * 4];

  s16x8 qf[2][2];
#pragma unroll
  for (int nt = 0; nt < 2; nt++)
#pragma unroll
    for (int ks = 0; ks < 2; ks++)
      qf[nt][ks] = *(const s16x8*)&Qg[(nt * 16 + c) * 64 + ks * 32 + quad * 8];

  int nq[2];
  nq[0] = nearest[b * 1024 + q0 + wq + c];
  nq[1] = nearest[b * 1024 + q0 + wq + 16 + c];

  f32x4 o[2][4];
#pragma unroll
  for (int i = 0; i < 2; i++)
#pragma unroll
    for (int j = 0; j < 4; j++) o[i][j] = (f32x4){0.f, 0.f, 0.f, 0.f};
  float lrun[2] = {0.f, 0.f};

  int srow = tid >> 3, scol8 = (tid & 7) * 8;

  u16x8 kr[2], vr[2];
#pragma unroll
  for (int it = 0; it < 2; ++it) {
    int r2 = it * 32 + srow;
    kr[it] = *(const u16x8*)&Kg[r2 * 64 + scol8];
    vr[it] = *(const u16x8*)&Vg[r2 * 1024 + scol8];
  }
  __syncthreads();   // Cb visible before first use

  for (int kc = 0; kc < 16; ++kc) {
#pragma unroll
    for (int it = 0; it < 2; ++it) {
      int r2 = it * 32 + srow;
      *(u16x8*)&Ks[r2 * 72 + scol8] = kr[it];
      *(u16x8*)&Vs[r2 * 72 + scol8] = vr[it];
    }
    __syncthreads();
    if (kc < 15) {
#pragma unroll
      for (int it = 0; it < 2; ++it) {
        int r2 = it * 32 + srow;
        kr[it] = *(const u16x8*)&Kg[((kc + 1) * 64 + r2) * 64 + scol8];
        vr[it] = *(const u16x8*)&Vg[r2 * 1024 + (kc + 1) * 64 + scol8];
      }
    }

    // S^T = K . Q^T : st[mt][nt] (key = mt*16+quad*4+r, q = nt*16+c)
    f32x4 st[4][2];
#pragma unroll
    for (int mt = 0; mt < 4; mt++)
#pragma unroll
      for (int nt = 0; nt < 2; nt++) st[mt][nt] = (f32x4){0.f, 0.f, 0.f, 0.f};
#pragma unroll
    for (int mt = 0; mt < 4; mt++)
#pragma unroll
      for (int ks = 0; ks < 2; ks++) {
        s16x8 a = *(const s16x8*)&Ks[(mt * 16 + c) * 72 + ks * 32 + quad * 8];
#pragma unroll
        for (int nt = 0; nt < 2; nt++)
          st[mt][nt] = __builtin_amdgcn_mfma_f32_16x16x32_bf16(a, qf[nt][ks], st[mt][nt], 0, 0, 0);
      }

    // bias + exp2 + partial row-sum + pack P -> LDS [q][key]
#pragma unroll
    for (int mt = 0; mt < 4; mt++) {
      f32x4 cb = *(const f32x4*)&Cb[kc * 64 + mt * 16 + quad * 4];
#pragma unroll
      for (int nt = 0; nt < 2; nt++) {
        u16x4 pk;
#pragma unroll
        for (int r = 0; r < 4; r++) {
          int keyg = kc * 64 + mt * 16 + quad * 4 + r;
          float x = st[mt][nt][r] + cb[r] + ((keyg == nq[nt]) ? VERB2 : 0.f);
          float e = EXP2F(x);
          lrun[nt] += e;
          pk[r] = f2bf(e);
        }
        *(u16x4*)&Ps[wid][(nt * 16 + c) * 72 + mt * 16 + quad * 4] = pk;
      }
    }
    __asm__ volatile("s_waitcnt lgkmcnt(0)" ::: "memory");

    // O += (P . V) computed SWAPPED: o[mtq][ntd] rows = d, cols = q
#pragma unroll
    for (int ks = 0; ks < 2; ks++) {
      s16x8 pa[2];
#pragma unroll
      for (int mtq = 0; mtq < 2; mtq++)
        pa[mtq] = *(const s16x8*)&Ps[wid][(mtq * 16 + c) * 72 + ks * 32 + quad * 8];
#pragma unroll
      for (int ntd = 0; ntd < 4; ntd++) {
        s16x8 vb = *(const s16x8*)&Vs[(ntd * 16 + c) * 72 + ks * 32 + quad * 8];
#pragma unroll
        for (int mtq = 0; mtq < 2; mtq++)
          o[mtq][ntd] = __builtin_amdgcn_mfma_f32_16x16x32_bf16(vb, pa[mtq], o[mtq][ntd], 0, 0, 0);
      }
    }
    __syncthreads();
  }

  // l-reduction across quads; lane's own token = mtq*16+c -> no shuffle
#pragma unroll
  for (int nt = 0; nt < 2; nt++) {
    lrun[nt] += __shfl_xor(lrun[nt], 16, 64);
    lrun[nt] += __shfl_xor(lrun[nt], 32, 64);
  }
  float linv[2] = {1.0f / lrun[0], 1.0f / lrun[1]};
#pragma unroll
  for (int mtq = 0; mtq < 2; mtq++) {
    size_t row = (size_t)(b * 1024 + q0 + wq + mtq * 16 + c);
#pragma unroll
    for (int ntd = 0; ntd < 4; ntd++) {
      int d0 = ntd * 16 + quad * 4;
      u16x4 pk;
#pragma unroll
      for (int r = 0; r < 4; r++) pk[r] = f2bf(o[mtq][ntd][r] * linv[mtq]);
      *(u16x4*)&AO[row * 1024 + head * 64 + d0] = pk;
    }
  }
}

// ---------------------------------------------------------------------------
extern "C" void kernel_launch(void* const* d_in, const int* in_sizes, int n_in,
                              void* d_out, int out_size, void* d_ws, size_t ws_size,
                              hipStream_t stream) {
  const float* hs     = (const float*)d_in[0];
  const int*   morpho = (const int*)d_in[1];
  const float* Wq = (const float*)d_in[2];
  const float* bq = (const float*)d_in[3];
  const float* Wk = (const float*)d_in[4];
  const float* bk = (const float*)d_in[5];
  const float* Wv = (const float*)d_in[6];
  const float* bv = (const float*)d_in[7];
  const float* Wo = (const float*)d_in[8];
  const float* bo = (const float*)d_in[9];
  float* out = (float*)d_out;

  char* ws = (char*)d_ws;
  unsigned short* hsb = (unsigned short*)(ws);                    // 8 MB [4096][1024]
  unsigned short* Wt  = (unsigned short*)(ws + (8u << 20));       // 8 MB [4][1024][1024]
  unsigned short* Qb  = (unsigned short*)(ws + (16u << 20));      // Q +16MB, K +24MB
  unsigned short* Kb  = (unsigned short*)(ws + (24u << 20));
  unsigned short* Vtb = (unsigned short*)(ws + (40u << 20));      // 8 MB [B,NH,HD,S]
  float* colbias      = (float*)(ws + (48u << 20));               // 16 KB
  int*   nearestp     = (int*)(ws + (48u << 20) + (16u << 10));   // 16 KB
  unsigned short* AO  = hsb;  // reuse: hs_bf16 dead after QKV GEMM

  k_prep<<<3088, 256, 0, stream>>>(hs, hsb, Wq, Wk, Wv, Wo, Wt, morpho,
                                   colbias, nearestp);
  k_gemm<0><<<dim3(24, 32), 256, 0, stream>>>(hsb, Wt, bq, bk, bv, Qb, Vtb, nullptr);
  k_attn<<<dim3(64, 8), 256, 0, stream>>>(Qb, Kb, Vtb, colbias, nearestp, AO);
  k_gemm<1><<<dim3(8, 64), 256, 0, stream>>>(AO, Wt + 3 * 1048576, bo, nullptr, nullptr,
                                             nullptr, nullptr, out);
  (void)in_sizes; (void)n_in; (void)out_size; (void)ws_size; (void)Kb;
}

// Round 7
// 214.650 us; speedup vs baseline: 1.3867x; 1.3867x over previous
//
#include <hip/hip_runtime.h>

// ---------------------------------------------------------------------------
// AgglutinativeAttention: hs->QKV proj -> morpho-biased softmax attn -> out proj
// B=4 S=1024 H=1024 NH=16 HD=64.  bf16 MFMA throughout.
// R7: GEMM = R3 single-buffer LDS structure + (a) XOR-swizzled staging to kill
//     the 8-way ds_read_b128 bank conflicts (3.1M cyc/dispatch measured),
//     (b) BK=64 (half the barriers), (c) gemm1 on 64x128 tiles (512 blocks).
//     Natural grid order (R4's XCD swizzle regressed). Vectorized epilogues.
// ---------------------------------------------------------------------------

#define QSCALE 0.18033688011112042f   /* 0.125 * log2(e) */
#define CB0    1.0820212806667225f    /* 0.75 * log2(e) */
#define CB1    0.5193702147200268f    /* 0.36 * log2(e) */
#define VERB2  2.8853900817779268f    /* 2.0  * log2(e) */

typedef float  f32x4   __attribute__((ext_vector_type(4)));
typedef short  s16x8   __attribute__((ext_vector_type(8)));
typedef unsigned short u16x4 __attribute__((ext_vector_type(4)));
typedef unsigned short u16x8 __attribute__((ext_vector_type(8)));

#if __has_builtin(__builtin_amdgcn_exp2f)
#define EXP2F(x) __builtin_amdgcn_exp2f(x)
#else
#define EXP2F(x) exp2f(x)
#endif

__device__ __forceinline__ unsigned short f2bf(float f) {
  union { float f; unsigned u; } a; a.f = f;
  unsigned r = a.u + 0x7fffu + ((a.u >> 16) & 1u);   // RNE
  return (unsigned short)(r >> 16);
}

__device__ __forceinline__ void async16(const void* g, void* l) {
  __builtin_amdgcn_global_load_lds(
      (const __attribute__((address_space(1))) unsigned int*)g,
      (__attribute__((address_space(3))) unsigned int*)l, 16, 0, 0);
}

// ---------------- fused prep: cvt (2048) | weight-T x4 (1024) | bias (16) ---
__global__ __launch_bounds__(256) void k_prep(
    const float* __restrict__ hs, unsigned short* __restrict__ hsb,
    const float* __restrict__ Wq, const float* __restrict__ Wk,
    const float* __restrict__ Wv, const float* __restrict__ Wo,
    unsigned short* __restrict__ Wt, const int* __restrict__ mt,
    float* __restrict__ colbias, int* __restrict__ nearest) {
  __shared__ float t[64 * 68];
  int bx = blockIdx.x, tid = threadIdx.x;
  if (bx < 2048) {
    int i = (bx * 256 + tid) * 8;
    float4 v0 = *(const float4*)(hs + i);
    float4 v1 = *(const float4*)(hs + i + 4);
    u16x8 o;
    o[0] = f2bf(v0.x); o[1] = f2bf(v0.y); o[2] = f2bf(v0.z); o[3] = f2bf(v0.w);
    o[4] = f2bf(v1.x); o[5] = f2bf(v1.y); o[6] = f2bf(v1.z); o[7] = f2bf(v1.w);
    *(u16x8*)(hsb + i) = o;
  } else if (bx < 3072) {
    int w = (bx - 2048) >> 8, tt = (bx - 2048) & 255;
    const float* W = (w == 0) ? Wq : (w == 1) ? Wk : (w == 2) ? Wv : Wo;
    unsigned short* Wd = Wt + (size_t)w * 1048576;
    int n0 = (tt & 15) * 64, k0 = (tt >> 4) * 64;
    int r = tid >> 2, c0 = (tid & 3) * 16;
    const float* src = &W[(k0 + r) * 1024 + n0 + c0];
    float4 a0 = *(const float4*)(src + 0);
    float4 a1 = *(const float4*)(src + 4);
    float4 a2 = *(const float4*)(src + 8);
    float4 a3 = *(const float4*)(src + 12);
    *(float4*)&t[r * 68 + c0 + 0]  = a0;
    *(float4*)&t[r * 68 + c0 + 4]  = a1;
    *(float4*)&t[r * 68 + c0 + 8]  = a2;
    *(float4*)&t[r * 68 + c0 + 12] = a3;
    __syncthreads();
    u16x8 o0, o1;
#pragma unroll
    for (int j = 0; j < 8; j++) {
      o0[j] = f2bf(t[(c0 + j) * 68 + r]);
      o1[j] = f2bf(t[(c0 + 8 + j) * 68 + r]);
    }
    *(u16x8*)&Wd[(n0 + r) * 1024 + k0 + c0]     = o0;
    *(u16x8*)&Wd[(n0 + r) * 1024 + k0 + c0 + 8] = o1;
  } else {
    int i = bx - 3072;
    int b = i >> 2;
    int* sm = (int*)t;
    for (int j = tid; j < 1024; j += 256) sm[j] = mt[b * 1024 + j];
    __syncthreads();
    int q = (i & 3) * 256 + tid;
    int best = 1 << 30, bj = -1;
    for (int j = 0; j < 1024; ++j) {
      int d = (q > j) ? (q - j) : (j - q);
      int dd = (sm[j] == 2) ? d : (1 << 30);
      if (dd < best) { best = dd; bj = j; }
    }
    nearest[b * 1024 + q] = bj;
    int m = sm[q];
    colbias[b * 1024 + q] = CB0 * (m == 0) + CB1 * (m == 1);
  }
}

// ---------------- MFMA GEMM, BK=64, XOR-swizzled staging --------------------
// LDS[row][chunk s] = global[row][chunk s ^ (row&7)]  (chunk = 16B = 8 bf16)
// Staging keeps global_load_lds contiguity (slot = lane*16); swizzle is purely
// in the per-lane global address. Fragment reads un-swizzle -> 2-way max bank
// aliasing (free).
// MODE 0: fused QKV, grid (24,32), 128x128 tiles. Q/K swapped operands ->
//         packed u16x4 [B,NH,S,HD]; V normal -> u16x4 into [B,NH,HD,S].
// MODE 1: out-proj, grid (8,64), 64x128 tiles; swapped -> float4 fp32 stores.
template <int MODE>
__global__ __launch_bounds__(256) void k_gemm(
    const unsigned short* __restrict__ A,
    const unsigned short* __restrict__ WtBase,
    const float* __restrict__ bias0, const float* __restrict__ bias1,
    const float* __restrict__ bias2,
    unsigned short* __restrict__ outB, unsigned short* __restrict__ outV,
    float* __restrict__ outF) {
  constexpr int TM = (MODE == 0) ? 128 : 64;
  constexpr int NI = (MODE == 0) ? 4 : 2;       // m-fragments per wave
  constexpr int RA = TM / 4;                    // A rows staged per wave
  __shared__ unsigned short As[TM * 64];
  __shared__ unsigned short Bs[128 * 64];
  int tid = threadIdx.x, wid = tid >> 6, lane = tid & 63;
  int c = lane & 15, quad = lane >> 4;
  int m0, wsel, n0;
  const unsigned short* Bt;
  const float* bias;
  if (MODE == 0) {
    wsel = blockIdx.x >> 3;
    n0 = (blockIdx.x & 7) * 128;
    m0 = blockIdx.y * 128;
    Bt = WtBase + wsel * 1048576;
    bias = (wsel == 0) ? bias0 : ((wsel == 1) ? bias1 : bias2);
  } else {
    wsel = 0;
    n0 = blockIdx.x * 128;
    m0 = blockIdx.y * 64;
    Bt = WtBase; bias = bias0;
  }
  int wm = (wid >> 1) * (16 * NI), wn = (wid & 1) * 64;
  int lr = lane >> 3, lc = lane & 7;
  int gcol = ((lc ^ lr) << 3);                  // XOR-swizzled 16B chunk
  const unsigned short* ga = A  + (size_t)(m0 + wid * RA + lr) * 1024 + gcol;
  const unsigned short* gb = Bt + (size_t)(n0 + wid * 32 + lr) * 1024 + gcol;
  unsigned short* lA = &As[(wid * RA) * 64];
  unsigned short* lB = &Bs[(wid * 32) * 64];

  f32x4 acc[NI][4];
#pragma unroll
  for (int i = 0; i < NI; i++)
#pragma unroll
    for (int j = 0; j < 4; j++) acc[i][j] = (f32x4){0.f, 0.f, 0.f, 0.f};

  bool sw = (MODE == 1) || (wsel != 2);         // swapped-operand (wave-uniform)

  for (int k0 = 0; k0 < 1024; k0 += 64) {
#pragma unroll
    for (int i = 0; i < RA / 8; i++) async16(ga + i * 8 * 1024 + k0, lA + i * 8 * 64);
#pragma unroll
    for (int j = 0; j < 4; j++)      async16(gb + j * 8 * 1024 + k0, lB + j * 8 * 64);
    __syncthreads();                             // staging visible (vmcnt drained)
#pragma unroll
    for (int ks = 0; ks < 2; ks++) {
      s16x8 af[NI], bf[4];
#pragma unroll
      for (int i = 0; i < NI; i++)
        af[i] = *(const s16x8*)&As[(wm + i * 16 + c) * 64 + (((ks * 4 + quad) ^ (c & 7)) << 3)];
#pragma unroll
      for (int j = 0; j < 4; j++)
        bf[j] = *(const s16x8*)&Bs[(wn + j * 16 + c) * 64 + (((ks * 4 + quad) ^ (c & 7)) << 3)];
      if (sw) {
#pragma unroll
        for (int i = 0; i < NI; i++)
#pragma unroll
          for (int j = 0; j < 4; j++)
            acc[i][j] = __builtin_amdgcn_mfma_f32_16x16x32_bf16(bf[j], af[i], acc[i][j], 0, 0, 0);
      } else {
#pragma unroll
        for (int i = 0; i < NI; i++)
#pragma unroll
          for (int j = 0; j < 4; j++)
            acc[i][j] = __builtin_amdgcn_mfma_f32_16x16x32_bf16(af[i], bf[j], acc[i][j], 0, 0, 0);
      }
    }
    __syncthreads();                             // all reads done before re-stage
  }

  if (MODE == 1) {
    // swapped: row=feature (4-contig), col=token -> float4 stores
#pragma unroll
    for (int j = 0; j < 4; j++) {
      int colb = n0 + wn + j * 16 + quad * 4;
      f32x4 bvv = *(const f32x4*)&bias[colb];
#pragma unroll
      for (int i = 0; i < NI; i++) {
        int s_tok = m0 + wm + i * 16 + c;
        f32x4 v = acc[i][j] + bvv;
        *(f32x4*)&outF[(size_t)s_tok * 1024 + colb] = v;
      }
    }
  } else if (wsel == 2) {
    // V normal order: row=token (4-contig) -> u16x4 into [b,h,d,s]
#pragma unroll
    for (int j = 0; j < 4; j++) {
      int col = n0 + wn + j * 16 + c;
      float bv = bias[col];
      int h = col >> 6, d = col & 63;
#pragma unroll
      for (int i = 0; i < NI; i++) {
        int row = m0 + wm + i * 16 + quad * 4;
        int bb = row >> 10, s = row & 1023;
        u16x4 pk;
#pragma unroll
        for (int r = 0; r < 4; r++) pk[r] = f2bf(acc[i][j][r] + bv);
        *(u16x4*)&outV[(size_t)(((bb * 16 + h) * 64 + d)) * 1024 + s] = pk;
      }
    }
  } else {
    // Q/K swapped: row=feature (4-contig), col=token -> u16x4 into [b,h,s,d]
    float sc = (wsel == 0) ? QSCALE : 1.0f;
#pragma unroll
    for (int j = 0; j < 4; j++) {
      int colb = n0 + wn + j * 16 + quad * 4;
      f32x4 bvv = *(const f32x4*)&bias[colb];
      int h = colb >> 6, d0 = colb & 63;
#pragma unroll
      for (int i = 0; i < NI; i++) {
        int s_tok = m0 + wm + i * 16 + c;
        int bb = s_tok >> 10, s = s_tok & 1023;
        u16x4 pk;
#pragma unroll
        for (int r = 0; r < 4; r++) pk[r] = f2bf((acc[i][j][r] + bvv[r]) * sc);
        *(u16x4*)&outB[(size_t)wsel * 4194304 + (((bb * 16 + h) * 1024 + s) * 64) + d0] = pk;
      }
    }
  }
}

// ---------------- Flash attention, 16x16x32 MFMA, streaming softmax ---------
// grid (bh=64, qt=8): all qt blocks of one bh land on one XCD. Register
// prefetch dbuf. PV swapped operands -> AO epilogue packed u16x4, no shuffle.
__global__ __launch_bounds__(256) void k_attn(
    const unsigned short* __restrict__ Q, const unsigned short* __restrict__ K,
    const unsigned short* __restrict__ Vt, const float* __restrict__ colbias,
    const int* __restrict__ nearest, unsigned short* __restrict__ AO) {
  __shared__ unsigned short Ks[64 * 72];     // [key][d]
  __shared__ unsigned short Vs[64 * 72];     // [d][key]
  __shared__ unsigned short Ps[4][32 * 72];  // per-wave [q][key]
  __shared__ float Cb[1024];
  int tid = threadIdx.x, wid = tid >> 6, lane = tid & 63;
  int c = lane & 15, quad = lane >> 4;
  int bh = blockIdx.x, qt = blockIdx.y;
  int b = bh >> 4, head = bh & 15;
  int q0 = qt * 128, wq = wid * 32;
  const unsigned short* Qg = Q  + (size_t)(bh * 1024 + q0 + wq) * 64;
  const unsigned short* Kg = K  + (size_t)bh * 1024 * 64;
  const unsigned short* Vg = Vt + (size_t)bh * 64 * 1024;

  *(float4*)&Cb[tid * 4] = *(const float4*)&colbias[b * 1024 + tid * 4];

  s16x8 qf[2][2];
#pragma unroll
  for (int nt = 0; nt < 2; nt++)
#pragma unroll
    for (int ks = 0; ks < 2; ks++)
      qf[nt][ks] = *(const s16x8*)&Qg[(nt * 16 + c) * 64 + ks * 32 + quad * 8];

  int nq[2];
  nq[0] = nearest[b * 1024 + q0 + wq + c];
  nq[1] = nearest[b * 1024 + q0 + wq + 16 + c];

  f32x4 o[2][4];
#pragma unroll
  for (int i = 0; i < 2; i++)
#pragma unroll
    for (int j = 0; j < 4; j++) o[i][j] = (f32x4){0.f, 0.f, 0.f, 0.f};
  float lrun[2] = {0.f, 0.f};

  int srow = tid >> 3, scol8 = (tid & 7) * 8;

  u16x8 kr[2], vr[2];
#pragma unroll
  for (int it = 0; it < 2; ++it) {
    int r2 = it * 32 + srow;
    kr[it] = *(const u16x8*)&Kg[r2 * 64 + scol8];
    vr[it] = *(const u16x8*)&Vg[r2 * 1024 + scol8];
  }
  __syncthreads();   // Cb visible before first use

  for (int kc = 0; kc < 16; ++kc) {
#pragma unroll
    for (int it = 0; it < 2; ++it) {
      int r2 = it * 32 + srow;
      *(u16x8*)&Ks[r2 * 72 + scol8] = kr[it];
      *(u16x8*)&Vs[r2 * 72 + scol8] = vr[it];
    }
    __syncthreads();
    if (kc < 15) {
#pragma unroll
      for (int it = 0; it < 2; ++it) {
        int r2 = it * 32 + srow;
        kr[it] = *(const u16x8*)&Kg[((kc + 1) * 64 + r2) * 64 + scol8];
        vr[it] = *(const u16x8*)&Vg[r2 * 1024 + (kc + 1) * 64 + scol8];
      }
    }

    // S^T = K . Q^T : st[mt][nt] (key = mt*16+quad*4+r, q = nt*16+c)
    f32x4 st[4][2];
#pragma unroll
    for (int mt = 0; mt < 4; mt++)
#pragma unroll
      for (int nt = 0; nt < 2; nt++) st[mt][nt] = (f32x4){0.f, 0.f, 0.f, 0.f};
#pragma unroll
    for (int mt = 0; mt < 4; mt++)
#pragma unroll
      for (int ks = 0; ks < 2; ks++) {
        s16x8 a = *(const s16x8*)&Ks[(mt * 16 + c) * 72 + ks * 32 + quad * 8];
#pragma unroll
        for (int nt = 0; nt < 2; nt++)
          st[mt][nt] = __builtin_amdgcn_mfma_f32_16x16x32_bf16(a, qf[nt][ks], st[mt][nt], 0, 0, 0);
      }

    // bias + exp2 + partial row-sum + pack P -> LDS [q][key]
#pragma unroll
    for (int mt = 0; mt < 4; mt++) {
      f32x4 cb = *(const f32x4*)&Cb[kc * 64 + mt * 16 + quad * 4];
#pragma unroll
      for (int nt = 0; nt < 2; nt++) {
        u16x4 pk;
#pragma unroll
        for (int r = 0; r < 4; r++) {
          int keyg = kc * 64 + mt * 16 + quad * 4 + r;
          float x = st[mt][nt][r] + cb[r] + ((keyg == nq[nt]) ? VERB2 : 0.f);
          float e = EXP2F(x);
          lrun[nt] += e;
          pk[r] = f2bf(e);
        }
        *(u16x4*)&Ps[wid][(nt * 16 + c) * 72 + mt * 16 + quad * 4] = pk;
      }
    }
    __asm__ volatile("s_waitcnt lgkmcnt(0)" ::: "memory");

    // O += (P . V) computed SWAPPED: o[mtq][ntd] rows = d, cols = q
#pragma unroll
    for (int ks = 0; ks < 2; ks++) {
      s16x8 pa[2];
#pragma unroll
      for (int mtq = 0; mtq < 2; mtq++)
        pa[mtq] = *(const s16x8*)&Ps[wid][(mtq * 16 + c) * 72 + ks * 32 + quad * 8];
#pragma unroll
      for (int ntd = 0; ntd < 4; ntd++) {
        s16x8 vb = *(const s16x8*)&Vs[(ntd * 16 + c) * 72 + ks * 32 + quad * 8];
#pragma unroll
        for (int mtq = 0; mtq < 2; mtq++)
          o[mtq][ntd] = __builtin_amdgcn_mfma_f32_16x16x32_bf16(vb, pa[mtq], o[mtq][ntd], 0, 0, 0);
      }
    }
    __syncthreads();
  }

  // l-reduction across quads; lane's own token = mtq*16+c -> no shuffle
#pragma unroll
  for (int nt = 0; nt < 2; nt++) {
    lrun[nt] += __shfl_xor(lrun[nt], 16, 64);
    lrun[nt] += __shfl_xor(lrun[nt], 32, 64);
  }
  float linv[2] = {1.0f / lrun[0], 1.0f / lrun[1]};
#pragma unroll
  for (int mtq = 0; mtq < 2; mtq++) {
    size_t row = (size_t)(b * 1024 + q0 + wq + mtq * 16 + c);
#pragma unroll
    for (int ntd = 0; ntd < 4; ntd++) {
      int d0 = ntd * 16 + quad * 4;
      u16x4 pk;
#pragma unroll
      for (int r = 0; r < 4; r++) pk[r] = f2bf(o[mtq][ntd][r] * linv[mtq]);
      *(u16x4*)&AO[row * 1024 + head * 64 + d0] = pk;
    }
  }
}

// ---------------------------------------------------------------------------
extern "C" void kernel_launch(void* const* d_in, const int* in_sizes, int n_in,
                              void* d_out, int out_size, void* d_ws, size_t ws_size,
                              hipStream_t stream) {
  const float* hs     = (const float*)d_in[0];
  const int*   morpho = (const int*)d_in[1];
  const float* Wq = (const float*)d_in[2];
  const float* bq = (const float*)d_in[3];
  const float* Wk = (const float*)d_in[4];
  const float* bk = (const float*)d_in[5];
  const float* Wv = (const float*)d_in[6];
  const float* bv = (const float*)d_in[7];
  const float* Wo = (const float*)d_in[8];
  const float* bo = (const float*)d_in[9];
  float* out = (float*)d_out;

  char* ws = (char*)d_ws;
  unsigned short* hsb = (unsigned short*)(ws);                    // 8 MB [4096][1024]
  unsigned short* Wt  = (unsigned short*)(ws + (8u << 20));       // 8 MB [4][1024][1024]
  unsigned short* Qb  = (unsigned short*)(ws + (16u << 20));      // Q +16MB, K +24MB
  unsigned short* Kb  = (unsigned short*)(ws + (24u << 20));
  unsigned short* Vtb = (unsigned short*)(ws + (40u << 20));      // 8 MB [B,NH,HD,S]
  float* colbias      = (float*)(ws + (48u << 20));               // 16 KB
  int*   nearestp     = (int*)(ws + (48u << 20) + (16u << 10));   // 16 KB
  unsigned short* AO  = hsb;  // reuse: hs_bf16 dead after QKV GEMM

  k_prep<<<3088, 256, 0, stream>>>(hs, hsb, Wq, Wk, Wv, Wo, Wt, morpho,
                                   colbias, nearestp);
  k_gemm<0><<<dim3(24, 32), 256, 0, stream>>>(hsb, Wt, bq, bk, bv, Qb, Vtb, nullptr);
  k_attn<<<dim3(64, 8), 256, 0, stream>>>(Qb, Kb, Vtb, colbias, nearestp, AO);
  k_gemm<1><<<dim3(8, 64), 256, 0, stream>>>(AO, Wt + 3 * 1048576, bo, nullptr, nullptr,
                                             nullptr, nullptr, out);
  (void)in_sizes; (void)n_in; (void)out_size; (void)ws_size; (void)Kb;
}

// Round 8
// 212.049 us; speedup vs baseline: 1.4037x; 1.0123x over previous
//
#include <hip/hip_runtime.h>

// ---------------------------------------------------------------------------
// AgglutinativeAttention: hs->QKV proj -> morpho-biased softmax attn -> out proj
// B=4 S=1024 H=1024 NH=16 HD=64.  bf16 MFMA throughout.
// R8: attn softmax VALU diet: (a) verb-bias check hoisted behind a wave-level
//     __any branch (taken ~2/16 chunks), (b) P packed to bf16 via v_perm
//     truncation (1 op / 2 elems, vs 4-op RNE f2bf), with l accumulated from
//     the packed values so the truncation bias cancels in O = PV/l.
//     GEMMs unchanged from R7 (XOR-swizzled staging, BK=64, 0 conflicts).
// ---------------------------------------------------------------------------

#define QSCALE 0.18033688011112042f   /* 0.125 * log2(e) */
#define CB0    1.0820212806667225f    /* 0.75 * log2(e) */
#define CB1    0.5193702147200268f    /* 0.36 * log2(e) */
#define VERB2  2.8853900817779268f    /* 2.0  * log2(e) */

typedef float  f32x4   __attribute__((ext_vector_type(4)));
typedef short  s16x8   __attribute__((ext_vector_type(8)));
typedef unsigned short u16x4 __attribute__((ext_vector_type(4)));
typedef unsigned short u16x8 __attribute__((ext_vector_type(8)));

#if __has_builtin(__builtin_amdgcn_exp2f)
#define EXP2F(x) __builtin_amdgcn_exp2f(x)
#else
#define EXP2F(x) exp2f(x)
#endif

__device__ __forceinline__ unsigned short f2bf(float f) {
  union { float f; unsigned u; } a; a.f = f;
  unsigned r = a.u + 0x7fffu + ((a.u >> 16) & 1u);   // RNE
  return (unsigned short)(r >> 16);
}

__device__ __forceinline__ void async16(const void* g, void* l) {
  __builtin_amdgcn_global_load_lds(
      (const __attribute__((address_space(1))) unsigned int*)g,
      (__attribute__((address_space(3))) unsigned int*)l, 16, 0, 0);
}

// ---------------- fused prep: cvt (2048) | weight-T x4 (1024) | bias (16) ---
__global__ __launch_bounds__(256) void k_prep(
    const float* __restrict__ hs, unsigned short* __restrict__ hsb,
    const float* __restrict__ Wq, const float* __restrict__ Wk,
    const float* __restrict__ Wv, const float* __restrict__ Wo,
    unsigned short* __restrict__ Wt, const int* __restrict__ mt,
    float* __restrict__ colbias, int* __restrict__ nearest) {
  __shared__ float t[64 * 68];
  int bx = blockIdx.x, tid = threadIdx.x;
  if (bx < 2048) {
    int i = (bx * 256 + tid) * 8;
    float4 v0 = *(const float4*)(hs + i);
    float4 v1 = *(const float4*)(hs + i + 4);
    u16x8 o;
    o[0] = f2bf(v0.x); o[1] = f2bf(v0.y); o[2] = f2bf(v0.z); o[3] = f2bf(v0.w);
    o[4] = f2bf(v1.x); o[5] = f2bf(v1.y); o[6] = f2bf(v1.z); o[7] = f2bf(v1.w);
    *(u16x8*)(hsb + i) = o;
  } else if (bx < 3072) {
    int w = (bx - 2048) >> 8, tt = (bx - 2048) & 255;
    const float* W = (w == 0) ? Wq : (w == 1) ? Wk : (w == 2) ? Wv : Wo;
    unsigned short* Wd = Wt + (size_t)w * 1048576;
    int n0 = (tt & 15) * 64, k0 = (tt >> 4) * 64;
    int r = tid >> 2, c0 = (tid & 3) * 16;
    const float* src = &W[(k0 + r) * 1024 + n0 + c0];
    float4 a0 = *(const float4*)(src + 0);
    float4 a1 = *(const float4*)(src + 4);
    float4 a2 = *(const float4*)(src + 8);
    float4 a3 = *(const float4*)(src + 12);
    *(float4*)&t[r * 68 + c0 + 0]  = a0;
    *(float4*)&t[r * 68 + c0 + 4]  = a1;
    *(float4*)&t[r * 68 + c0 + 8]  = a2;
    *(float4*)&t[r * 68 + c0 + 12] = a3;
    __syncthreads();
    u16x8 o0, o1;
#pragma unroll
    for (int j = 0; j < 8; j++) {
      o0[j] = f2bf(t[(c0 + j) * 68 + r]);
      o1[j] = f2bf(t[(c0 + 8 + j) * 68 + r]);
    }
    *(u16x8*)&Wd[(n0 + r) * 1024 + k0 + c0]     = o0;
    *(u16x8*)&Wd[(n0 + r) * 1024 + k0 + c0 + 8] = o1;
  } else {
    int i = bx - 3072;
    int b = i >> 2;
    int* sm = (int*)t;
    for (int j = tid; j < 1024; j += 256) sm[j] = mt[b * 1024 + j];
    __syncthreads();
    int q = (i & 3) * 256 + tid;
    int best = 1 << 30, bj = -1;
    for (int j = 0; j < 1024; ++j) {
      int d = (q > j) ? (q - j) : (j - q);
      int dd = (sm[j] == 2) ? d : (1 << 30);
      if (dd < best) { best = dd; bj = j; }
    }
    nearest[b * 1024 + q] = bj;
    int m = sm[q];
    colbias[b * 1024 + q] = CB0 * (m == 0) + CB1 * (m == 1);
  }
}

// ---------------- MFMA GEMM, BK=64, XOR-swizzled staging --------------------
// LDS[row][chunk s] = global[row][chunk s ^ (row&7)]  (chunk = 16B = 8 bf16)
// MODE 0: fused QKV, grid (24,32), 128x128 tiles. Q/K swapped operands ->
//         packed u16x4 [B,NH,S,HD]; V normal -> u16x4 into [B,NH,HD,S].
// MODE 1: out-proj, grid (8,64), 64x128 tiles; swapped -> float4 fp32 stores.
template <int MODE>
__global__ __launch_bounds__(256) void k_gemm(
    const unsigned short* __restrict__ A,
    const unsigned short* __restrict__ WtBase,
    const float* __restrict__ bias0, const float* __restrict__ bias1,
    const float* __restrict__ bias2,
    unsigned short* __restrict__ outB, unsigned short* __restrict__ outV,
    float* __restrict__ outF) {
  constexpr int TM = (MODE == 0) ? 128 : 64;
  constexpr int NI = (MODE == 0) ? 4 : 2;       // m-fragments per wave
  constexpr int RA = TM / 4;                    // A rows staged per wave
  __shared__ unsigned short As[TM * 64];
  __shared__ unsigned short Bs[128 * 64];
  int tid = threadIdx.x, wid = tid >> 6, lane = tid & 63;
  int c = lane & 15, quad = lane >> 4;
  int m0, wsel, n0;
  const unsigned short* Bt;
  const float* bias;
  if (MODE == 0) {
    wsel = blockIdx.x >> 3;
    n0 = (blockIdx.x & 7) * 128;
    m0 = blockIdx.y * 128;
    Bt = WtBase + wsel * 1048576;
    bias = (wsel == 0) ? bias0 : ((wsel == 1) ? bias1 : bias2);
  } else {
    wsel = 0;
    n0 = blockIdx.x * 128;
    m0 = blockIdx.y * 64;
    Bt = WtBase; bias = bias0;
  }
  int wm = (wid >> 1) * (16 * NI), wn = (wid & 1) * 64;
  int lr = lane >> 3, lc = lane & 7;
  int gcol = ((lc ^ lr) << 3);                  // XOR-swizzled 16B chunk
  const unsigned short* ga = A  + (size_t)(m0 + wid * RA + lr) * 1024 + gcol;
  const unsigned short* gb = Bt + (size_t)(n0 + wid * 32 + lr) * 1024 + gcol;
  unsigned short* lA = &As[(wid * RA) * 64];
  unsigned short* lB = &Bs[(wid * 32) * 64];

  f32x4 acc[NI][4];
#pragma unroll
  for (int i = 0; i < NI; i++)
#pragma unroll
    for (int j = 0; j < 4; j++) acc[i][j] = (f32x4){0.f, 0.f, 0.f, 0.f};

  bool sw = (MODE == 1) || (wsel != 2);         // swapped-operand (wave-uniform)

  for (int k0 = 0; k0 < 1024; k0 += 64) {
#pragma unroll
    for (int i = 0; i < RA / 8; i++) async16(ga + i * 8 * 1024 + k0, lA + i * 8 * 64);
#pragma unroll
    for (int j = 0; j < 4; j++)      async16(gb + j * 8 * 1024 + k0, lB + j * 8 * 64);
    __syncthreads();                             // staging visible (vmcnt drained)
#pragma unroll
    for (int ks = 0; ks < 2; ks++) {
      s16x8 af[NI], bf[4];
#pragma unroll
      for (int i = 0; i < NI; i++)
        af[i] = *(const s16x8*)&As[(wm + i * 16 + c) * 64 + (((ks * 4 + quad) ^ (c & 7)) << 3)];
#pragma unroll
      for (int j = 0; j < 4; j++)
        bf[j] = *(const s16x8*)&Bs[(wn + j * 16 + c) * 64 + (((ks * 4 + quad) ^ (c & 7)) << 3)];
      if (sw) {
#pragma unroll
        for (int i = 0; i < NI; i++)
#pragma unroll
          for (int j = 0; j < 4; j++)
            acc[i][j] = __builtin_amdgcn_mfma_f32_16x16x32_bf16(bf[j], af[i], acc[i][j], 0, 0, 0);
      } else {
#pragma unroll
        for (int i = 0; i < NI; i++)
#pragma unroll
          for (int j = 0; j < 4; j++)
            acc[i][j] = __builtin_amdgcn_mfma_f32_16x16x32_bf16(af[i], bf[j], acc[i][j], 0, 0, 0);
      }
    }
    __syncthreads();                             // all reads done before re-stage
  }

  if (MODE == 1) {
    // swapped: row=feature (4-contig), col=token -> float4 stores
#pragma unroll
    for (int j = 0; j < 4; j++) {
      int colb = n0 + wn + j * 16 + quad * 4;
      f32x4 bvv = *(const f32x4*)&bias[colb];
#pragma unroll
      for (int i = 0; i < NI; i++) {
        int s_tok = m0 + wm + i * 16 + c;
        f32x4 v = acc[i][j] + bvv;
        *(f32x4*)&outF[(size_t)s_tok * 1024 + colb] = v;
      }
    }
  } else if (wsel == 2) {
    // V normal order: row=token (4-contig) -> u16x4 into [b,h,d,s]
#pragma unroll
    for (int j = 0; j < 4; j++) {
      int col = n0 + wn + j * 16 + c;
      float bv = bias[col];
      int h = col >> 6, d = col & 63;
#pragma unroll
      for (int i = 0; i < NI; i++) {
        int row = m0 + wm + i * 16 + quad * 4;
        int bb = row >> 10, s = row & 1023;
        u16x4 pk;
#pragma unroll
        for (int r = 0; r < 4; r++) pk[r] = f2bf(acc[i][j][r] + bv);
        *(u16x4*)&outV[(size_t)(((bb * 16 + h) * 64 + d)) * 1024 + s] = pk;
      }
    }
  } else {
    // Q/K swapped: row=feature (4-contig), col=token -> u16x4 into [b,h,s,d]
    float sc = (wsel == 0) ? QSCALE : 1.0f;
#pragma unroll
    for (int j = 0; j < 4; j++) {
      int colb = n0 + wn + j * 16 + quad * 4;
      f32x4 bvv = *(const f32x4*)&bias[colb];
      int h = colb >> 6, d0 = colb & 63;
#pragma unroll
      for (int i = 0; i < NI; i++) {
        int s_tok = m0 + wm + i * 16 + c;
        int bb = s_tok >> 10, s = s_tok & 1023;
        u16x4 pk;
#pragma unroll
        for (int r = 0; r < 4; r++) pk[r] = f2bf((acc[i][j][r] + bvv[r]) * sc);
        *(u16x4*)&outB[(size_t)wsel * 4194304 + (((bb * 16 + h) * 1024 + s) * 64) + d0] = pk;
      }
    }
  }
}

// ---------------- Flash attention, 16x16x32 MFMA, streaming softmax ---------
// grid (bh=64, qt=8): all qt blocks of one bh land on one XCD. Register
// prefetch dbuf. PV swapped operands -> AO epilogue packed u16x4, no shuffle.
// Softmax hot path: add colbias, exp2, v_perm truncate-pack; l accumulated
// from packed values (consistency => truncation bias cancels in O = PV/l).
// Verb bias applied in a rare wave-level branch (nq hits one chunk of 16).
__global__ __launch_bounds__(256) void k_attn(
    const unsigned short* __restrict__ Q, const unsigned short* __restrict__ K,
    const unsigned short* __restrict__ Vt, const float* __restrict__ colbias,
    const int* __restrict__ nearest, unsigned short* __restrict__ AO) {
  __shared__ unsigned short Ks[64 * 72];     // [key][d]
  __shared__ unsigned short Vs[64 * 72];     // [d][key]
  __shared__ unsigned short Ps[4][32 * 72];  // per-wave [q][key]
  __shared__ float Cb[1024];
  int tid = threadIdx.x, wid = tid >> 6, lane = tid & 63;
  int c = lane & 15, quad = lane >> 4;
  int bh = blockIdx.x, qt = blockIdx.y;
  int b = bh >> 4, head = bh & 15;
  int q0 = qt * 128, wq = wid * 32;
  const unsigned short* Qg = Q  + (size_t)(bh * 1024 + q0 + wq) * 64;
  const unsigned short* Kg = K  + (size_t)bh * 1024 * 64;
  const unsigned short* Vg = Vt + (size_t)bh * 64 * 1024;

  *(float4*)&Cb[tid * 4] = *(const float4*)&colbias[b * 1024 + tid * 4];

  s16x8 qf[2][2];
#pragma unroll
  for (int nt = 0; nt < 2; nt++)
#pragma unroll
    for (int ks = 0; ks < 2; ks++)
      qf[nt][ks] = *(const s16x8*)&Qg[(nt * 16 + c) * 64 + ks * 32 + quad * 8];

  int nq[2];
  nq[0] = nearest[b * 1024 + q0 + wq + c];
  nq[1] = nearest[b * 1024 + q0 + wq + 16 + c];

  f32x4 o[2][4];
#pragma unroll
  for (int i = 0; i < 2; i++)
#pragma unroll
    for (int j = 0; j < 4; j++) o[i][j] = (f32x4){0.f, 0.f, 0.f, 0.f};
  float lrun[2] = {0.f, 0.f};

  int srow = tid >> 3, scol8 = (tid & 7) * 8;

  u16x8 kr[2], vr[2];
#pragma unroll
  for (int it = 0; it < 2; ++it) {
    int r2 = it * 32 + srow;
    kr[it] = *(const u16x8*)&Kg[r2 * 64 + scol8];
    vr[it] = *(const u16x8*)&Vg[r2 * 1024 + scol8];
  }
  __syncthreads();   // Cb visible before first use

  for (int kc = 0; kc < 16; ++kc) {
#pragma unroll
    for (int it = 0; it < 2; ++it) {
      int r2 = it * 32 + srow;
      *(u16x8*)&Ks[r2 * 72 + scol8] = kr[it];
      *(u16x8*)&Vs[r2 * 72 + scol8] = vr[it];
    }
    __syncthreads();
    if (kc < 15) {
#pragma unroll
      for (int it = 0; it < 2; ++it) {
        int r2 = it * 32 + srow;
        kr[it] = *(const u16x8*)&Kg[((kc + 1) * 64 + r2) * 64 + scol8];
        vr[it] = *(const u16x8*)&Vg[r2 * 1024 + (kc + 1) * 64 + scol8];
      }
    }

    // S^T = K . Q^T : st[mt][nt] (key = mt*16+quad*4+r, q = nt*16+c)
    f32x4 st[4][2];
#pragma unroll
    for (int mt = 0; mt < 4; mt++)
#pragma unroll
      for (int nt = 0; nt < 2; nt++) st[mt][nt] = (f32x4){0.f, 0.f, 0.f, 0.f};
#pragma unroll
    for (int mt = 0; mt < 4; mt++)
#pragma unroll
      for (int ks = 0; ks < 2; ks++) {
        s16x8 a = *(const s16x8*)&Ks[(mt * 16 + c) * 72 + ks * 32 + quad * 8];
#pragma unroll
        for (int nt = 0; nt < 2; nt++)
          st[mt][nt] = __builtin_amdgcn_mfma_f32_16x16x32_bf16(a, qf[nt][ks], st[mt][nt], 0, 0, 0);
      }

    // rare verb-bias fixup: nq lands in this chunk for at most one element
    bool h0 = (nq[0] >> 6) == kc;
    bool h1 = (nq[1] >> 6) == kc;
    if (__any(h0 || h1)) {
#pragma unroll
      for (int mt = 0; mt < 4; mt++)
#pragma unroll
        for (int nt = 0; nt < 2; nt++)
#pragma unroll
          for (int r = 0; r < 4; r++)
            if (kc * 64 + mt * 16 + quad * 4 + r == nq[nt]) st[mt][nt][r] += VERB2;
    }

    // hot path: cb add + exp2 + v_perm truncate-pack; l from packed values
#pragma unroll
    for (int mt = 0; mt < 4; mt++) {
      f32x4 cb = *(const f32x4*)&Cb[kc * 64 + mt * 16 + quad * 4];
#pragma unroll
      for (int nt = 0; nt < 2; nt++) {
        float e0 = EXP2F(st[mt][nt][0] + cb[0]);
        float e1 = EXP2F(st[mt][nt][1] + cb[1]);
        float e2 = EXP2F(st[mt][nt][2] + cb[2]);
        float e3 = EXP2F(st[mt][nt][3] + cb[3]);
        unsigned p01 = __builtin_amdgcn_perm(__float_as_uint(e1), __float_as_uint(e0), 0x07060302u);
        unsigned p23 = __builtin_amdgcn_perm(__float_as_uint(e3), __float_as_uint(e2), 0x07060302u);
        lrun[nt] += __uint_as_float(p01 << 16) + __uint_as_float(p01 & 0xffff0000u)
                  + __uint_as_float(p23 << 16) + __uint_as_float(p23 & 0xffff0000u);
        uint2 pk; pk.x = p01; pk.y = p23;
        *(uint2*)&Ps[wid][(nt * 16 + c) * 72 + mt * 16 + quad * 4] = pk;
      }
    }
    __asm__ volatile("s_waitcnt lgkmcnt(0)" ::: "memory");

    // O += (P . V) computed SWAPPED: o[mtq][ntd] rows = d, cols = q
#pragma unroll
    for (int ks = 0; ks < 2; ks++) {
      s16x8 pa[2];
#pragma unroll
      for (int mtq = 0; mtq < 2; mtq++)
        pa[mtq] = *(const s16x8*)&Ps[wid][(mtq * 16 + c) * 72 + ks * 32 + quad * 8];
#pragma unroll
      for (int ntd = 0; ntd < 4; ntd++) {
        s16x8 vb = *(const s16x8*)&Vs[(ntd * 16 + c) * 72 + ks * 32 + quad * 8];
#pragma unroll
        for (int mtq = 0; mtq < 2; mtq++)
          o[mtq][ntd] = __builtin_amdgcn_mfma_f32_16x16x32_bf16(vb, pa[mtq], o[mtq][ntd], 0, 0, 0);
      }
    }
    __syncthreads();
  }

  // l-reduction across quads; lane's own token = mtq*16+c -> no shuffle
#pragma unroll
  for (int nt = 0; nt < 2; nt++) {
    lrun[nt] += __shfl_xor(lrun[nt], 16, 64);
    lrun[nt] += __shfl_xor(lrun[nt], 32, 64);
  }
  float linv[2] = {1.0f / lrun[0], 1.0f / lrun[1]};
#pragma unroll
  for (int mtq = 0; mtq < 2; mtq++) {
    size_t row = (size_t)(b * 1024 + q0 + wq + mtq * 16 + c);
#pragma unroll
    for (int ntd = 0; ntd < 4; ntd++) {
      int d0 = ntd * 16 + quad * 4;
      u16x4 pk;
#pragma unroll
      for (int r = 0; r < 4; r++) pk[r] = f2bf(o[mtq][ntd][r] * linv[mtq]);
      *(u16x4*)&AO[row * 1024 + head * 64 + d0] = pk;
    }
  }
}

// ---------------------------------------------------------------------------
extern "C" void kernel_launch(void* const* d_in, const int* in_sizes, int n_in,
                              void* d_out, int out_size, void* d_ws, size_t ws_size,
                              hipStream_t stream) {
  const float* hs     = (const float*)d_in[0];
  const int*   morpho = (const int*)d_in[1];
  const float* Wq = (const float*)d_in[2];
  const float* bq = (const float*)d_in[3];
  const float* Wk = (const float*)d_in[4];
  const float* bk = (const float*)d_in[5];
  const float* Wv = (const float*)d_in[6];
  const float* bv = (const float*)d_in[7];
  const float* Wo = (const float*)d_in[8];
  const float* bo = (const float*)d_in[9];
  float* out = (float*)d_out;

  char* ws = (char*)d_ws;
  unsigned short* hsb = (unsigned short*)(ws);                    // 8 MB [4096][1024]
  unsigned short* Wt  = (unsigned short*)(ws + (8u << 20));       // 8 MB [4][1024][1024]
  unsigned short* Qb  = (unsigned short*)(ws + (16u << 20));      // Q +16MB, K +24MB
  unsigned short* Kb  = (unsigned short*)(ws + (24u << 20));
  unsigned short* Vtb = (unsigned short*)(ws + (40u << 20));      // 8 MB [B,NH,HD,S]
  float* colbias      = (float*)(ws + (48u << 20));               // 16 KB
  int*   nearestp     = (int*)(ws + (48u << 20) + (16u << 10));   // 16 KB
  unsigned short* AO  = hsb;  // reuse: hs_bf16 dead after QKV GEMM

  k_prep<<<3088, 256, 0, stream>>>(hs, hsb, Wq, Wk, Wv, Wo, Wt, morpho,
                                   colbias, nearestp);
  k_gemm<0><<<dim3(24, 32), 256, 0, stream>>>(hsb, Wt, bq, bk, bv, Qb, Vtb, nullptr);
  k_attn<<<dim3(64, 8), 256, 0, stream>>>(Qb, Kb, Vtb, colbias, nearestp, AO);
  k_gemm<1><<<dim3(8, 64), 256, 0, stream>>>(AO, Wt + 3 * 1048576, bo, nullptr, nullptr,
                                             nullptr, nullptr, out);
  (void)in_sizes; (void)n_in; (void)out_size; (void)ws_size; (void)Kb;
}